// Round 5
// baseline (285.286 us; speedup 1.0000x reference)
//
#include <hip/hip_runtime.h>
#include <math.h>

#define SEQ    4096
#define DMODEL 1024
#define NHEADS 16
#define DK     64

typedef unsigned short u16;
typedef short bh8 __attribute__((ext_vector_type(8)));   // 8 x bf16 (4 VGPRs)
typedef float f4  __attribute__((ext_vector_type(4)));   // 4 x fp32 acc

__device__ __forceinline__ u16 f2b(float f) {            // RNE
    union { float f; unsigned u; } v; v.f = f;
    unsigned u = v.u;
    return (u16)((u + 0x7FFFu + ((u >> 16) & 1u)) >> 16);
}
__device__ __forceinline__ unsigned pk2(float a, float b) {  // trunc pack 2xbf16
    union { float f; unsigned u; } ua, ub; ua.f = a; ub.f = b;
    return (ua.u >> 16) | (ub.u & 0xFFFF0000u);
}

// ---------------------------------------------------------------------------
// Merged fp32 -> bf16 convert for x and all 4 weights (one launch).
// ---------------------------------------------------------------------------
__global__ void cvt_all_kernel(const float* __restrict__ x,
                               const float* __restrict__ wq, const float* __restrict__ wk,
                               const float* __restrict__ wv, const float* __restrict__ wo,
                               u16* __restrict__ xb, u16* __restrict__ wb)
{
    const int NX = SEQ * DMODEL / 8;        // 524288 chunks of 8
    const int NW = DMODEL * DMODEL / 8;     // 131072
    int i = blockIdx.x * blockDim.x + threadIdx.x;
    if (i >= NX + 4 * NW) return;
    const float* src; u16* dst; int j;
    if (i < NX) { src = x; dst = xb; j = i; }
    else {
        int k = i - NX;
        int wsel = k >> 17;                 // NW = 2^17
        j = k & (NW - 1);
        src = (wsel == 0) ? wq : (wsel == 1) ? wk : (wsel == 2) ? wv : wo;
        dst = wb + (size_t)wsel * DMODEL * DMODEL;
    }
    const float4* p = (const float4*)src + (size_t)j * 2;
    float4 a = p[0], b = p[1];
    __align__(16) u16 r[8] = { f2b(a.x), f2b(a.y), f2b(a.z), f2b(a.w),
                               f2b(b.x), f2b(b.y), f2b(b.z), f2b(b.w) };
    *(uint4*)(dst + (size_t)j * 8) = *(const uint4*)r;
}

// ---------------------------------------------------------------------------
// RoPE cos/sin table: tab[s][f] = (cos, sin) via the SAME v_sin revolutions
// formula the fused epilogue used (numerically identical).
// ---------------------------------------------------------------------------
__global__ void rope_build_kernel(float2* __restrict__ tab)
{
    int i = blockIdx.x * blockDim.x + threadIdx.x;     // 4096*32
    int s = i >> 5, f = i & 31;
    float invf2 = exp2f((float)(2 * f) * (-13.287712379549449f / 64.0f))
                  * 0.15915494309189535f;
    float rev = (float)s * invf2;
    rev -= floorf(rev);
    float2 cs;
    cs.x = __builtin_amdgcn_cosf(rev);
    cs.y = __builtin_amdgcn_sinf(rev);
    tab[i] = cs;
}

// ---------------------------------------------------------------------------
// bf16 MFMA GEMM (bt-form), BK=32, 4 waves.
// MODE 0: 128x64 tile, fp32 out.  MODE 2: 128x128, fused QKV epilogue
// (Q: RoPE (table) * 0.125*log2e pre-scale -> [h][s][64]; K: RoPE -> [h][s][64];
//  V: transposed -> [h][64][s]).
// ---------------------------------------------------------------------------
template<int MODE>
__global__ __launch_bounds__(256) void gemm_bt(
    const u16* __restrict__ A, const u16* __restrict__ B,
    void* __restrict__ out, u16* __restrict__ Qh, u16* __restrict__ Kh,
    u16* __restrict__ Vt, const float2* __restrict__ rope, int M, int N, int K)
{
    constexpr int BN = (MODE == 0) ? 64 : 128;
    constexpr int NJ = BN / 32;             // j-tiles per wave (2 or 4)

    __shared__ __align__(16) u16 As[128 * 32];
    __shared__ __align__(16) u16 Bs[BN * 32];

    const int t    = threadIdx.x;
    const int w    = t >> 6, lane = t & 63;
    const int quad = lane >> 4, l16 = lane & 15;
    const int wm   = w >> 1,  wn  = w & 1;
    const int m0   = blockIdx.y * 128, n0 = blockIdx.x * BN;
    const int lr   = lane >> 2;             // 0..15
    const int lc   = (lane & 3) * 8;        // 0,8,16,24

    f4 acc[4][NJ];
#pragma unroll
    for (int i = 0; i < 4; ++i)
#pragma unroll
        for (int j = 0; j < NJ; ++j) { f4 z = {0.f,0.f,0.f,0.f}; acc[i][j] = z; }

    const int c0 = 2 * w, c1 = 2 * w + 1;

    for (int k0 = 0; k0 < K; k0 += 32) {
        __builtin_amdgcn_global_load_lds(
            (const __attribute__((address_space(1))) unsigned int*)(A + (size_t)(m0 + c0*16 + lr)*K + k0 + lc),
            (__attribute__((address_space(3))) unsigned int*)(As + c0*512), 16, 0, 0);
        __builtin_amdgcn_global_load_lds(
            (const __attribute__((address_space(1))) unsigned int*)(A + (size_t)(m0 + c1*16 + lr)*K + k0 + lc),
            (__attribute__((address_space(3))) unsigned int*)(As + c1*512), 16, 0, 0);
        if (MODE == 0) {
            __builtin_amdgcn_global_load_lds(
                (const __attribute__((address_space(1))) unsigned int*)(B + (size_t)(n0 + w*16 + lr)*K + k0 + lc),
                (__attribute__((address_space(3))) unsigned int*)(Bs + w*512), 16, 0, 0);
        } else {
            __builtin_amdgcn_global_load_lds(
                (const __attribute__((address_space(1))) unsigned int*)(B + (size_t)(n0 + c0*16 + lr)*K + k0 + lc),
                (__attribute__((address_space(3))) unsigned int*)(Bs + c0*512), 16, 0, 0);
            __builtin_amdgcn_global_load_lds(
                (const __attribute__((address_space(1))) unsigned int*)(B + (size_t)(n0 + c1*16 + lr)*K + k0 + lc),
                (__attribute__((address_space(3))) unsigned int*)(Bs + c1*512), 16, 0, 0);
        }
        __syncthreads();

        bh8 af[4], bf_[NJ];
#pragma unroll
        for (int i = 0; i < 4; ++i)
            af[i] = *(const bh8*)&As[(wm*64 + i*16 + l16)*32 + quad*8];
#pragma unroll
        for (int j = 0; j < NJ; ++j)
            bf_[j] = *(const bh8*)&Bs[(wn*(BN/2) + j*16 + l16)*32 + quad*8];
#pragma unroll
        for (int i = 0; i < 4; ++i)
#pragma unroll
            for (int j = 0; j < NJ; ++j)
                acc[i][j] = __builtin_amdgcn_mfma_f32_16x16x32_bf16(af[i], bf_[j], acc[i][j], 0, 0, 0);
        __syncthreads();
    }

    if (MODE == 0) {
#pragma unroll
        for (int i = 0; i < 4; ++i) {
            const int row = m0 + wm*64 + i*16 + quad*4;
#pragma unroll
            for (int j = 0; j < NJ; ++j) {
                const int col = n0 + wn*(BN/2) + j*16 + l16;
#pragma unroll
                for (int r = 0; r < 4; ++r)
                    ((float*)out)[(size_t)(row + r) * N + col] = acc[i][j][r];
            }
        }
    } else {
        const int sect  = n0 >> 10;                   // 0=Q,1=K,2=V (block-uniform)
        const int cbase = (n0 & 1023) + wn * 64;      // 64-aligned head base
        const int hh    = cbase >> 6;                 // head (wave-uniform)
        if (sect < 2) {
            u16* dst = (sect == 0) ? Qh : Kh;
            const float qscl = (sect == 0) ? 0.18033688011112042f : 1.0f; // 0.125*log2(e)
#pragma unroll
            for (int j = 0; j < NJ; ++j) {
                const int d  = j * 16 + l16;          // 0..63 within head
                const int fr = j * 8 + (l16 >> 1);    // freq index d>>1
#pragma unroll
                for (int i = 0; i < 4; ++i) {
                    const int srow0 = m0 + wm*64 + i*16 + quad*4;
#pragma unroll
                    for (int r = 0; r < 4; ++r) {
                        float own = acc[i][j][r];
                        float oth = __shfl_xor(own, 1);      // rope pair partner
                        float2 cssn = rope[(size_t)(srow0 + r) * 32 + fr];
                        const float cs = cssn.x, sn = cssn.y;
                        float xe = (l16 & 1) ? oth : own;
                        float xo = (l16 & 1) ? own : oth;
                        float val = (l16 & 1) ? (sn * xe + cs * xo)
                                              : (cs * xe - sn * xo);
                        dst[((size_t)hh * SEQ + srow0 + r) * DK + d] = f2b(val * qscl);
                    }
                }
            }
        } else {
#pragma unroll
            for (int j = 0; j < NJ; ++j) {
                const int d = j * 16 + l16;
#pragma unroll
                for (int i = 0; i < 4; ++i) {
                    const int srow0 = m0 + wm*64 + i*16 + quad*4;
                    __align__(8) u16 pk[4];
#pragma unroll
                    for (int r = 0; r < 4; ++r) pk[r] = f2b(acc[i][j][r]);
                    *(unsigned long long*)&Vt[((size_t)hh * DK + d) * SEQ + srow0] =
                        *(const unsigned long long*)pk;
                }
            }
        }
    }
}

// ---------------------------------------------------------------------------
// MFMA flash attention, register-resident P and K.
// R5 = R4 with the epilogue-scratch overflow fixed: merge scratch is now a
// DEDICATED 20KB LDS array (4 wave-pairs x 64 lanes x 20 floats, stride-20
// conflict-free) instead of aliasing the 8KB Vs halves (R4 overflowed Vs ->
// corrupted O partials, absmax 0.64).
// K never touches LDS: each wave loads its 4 K fragments global->regs
// (L2-hot), double-buffered in named registers, prefetch distance 1.
// V: coalesced uint4 read at step top, permuted+swizzled uint2 ds_writes
// after PV (conflict-free). 8-wave blocks, key-half split (hh), additive
// O/l merge (softmax is max-free). Grid (32, NHEADS): qt=bx then 63-bx.
// ---------------------------------------------------------------------------
__global__ __launch_bounds__(512) void attn_mfma_kernel(
    const u16* __restrict__ Qh, const u16* __restrict__ Kh,
    const u16* __restrict__ Vt, u16* __restrict__ ctx)
{
    __shared__ __align__(16) u16 Vs[2][64 * 64];    // [d][key'] (permuted+swizzled)
    __shared__ __align__(16) float mscr[4 * 64 * 20]; // merge scratch (20KB)

    const int h    = blockIdx.y;
    const int bx   = blockIdx.x;                   // 0..31
    const int t    = threadIdx.x;                  // 0..511
    const int w    = t >> 6, lane = t & 63;
    const int wl   = w & 3, hh = w >> 2;           // q-slice, key-half
    const int quad = lane >> 4, l16 = lane & 15;

    const u16* Kbase = Kh + (size_t)h * SEQ * DK;
    const u16* Vbase = Vt + (size_t)h * DK * SEQ;

    // V-fragment swizzled column offsets (u16 units): logical 16B slot L at
    // row r lives at physical slot L ^ (r&7); fragment rows have low3 = l16&7.
    const int sA = ((quad       ^ (l16 & 7)) * 8);   // slots 0..3 (kbp=0)
    const int sB = (((4 + quad) ^ (l16 & 7)) * 8);   // slots 4..7 (kbp=1)

    // K fragment base pointers (global, per wave): kb in {2hh, 2hh+1},
    // d-halves {0,32}. Advanced by 64*DK per k-tile.
    const u16* kp[4];
#pragma unroll
    for (int kk = 0; kk < 2; ++kk)
#pragma unroll
        for (int hf = 0; hf < 2; ++hf)
            kp[kk * 2 + hf] = Kbase + (size_t)((hh * 2 + kk) * 16 + l16) * DK
                              + hf * 32 + quad * 8;

    // V staging: thread t owns row d = t>>3, 16B source group c2 = t&7
    // (keys c2*8..c2*8+7). The uint4 splits into two 4-key chunks written at
    // permuted kappas (kbp=key>>5, jhi=(key>>4)&1, q=(key>>2)&3, jl=key&3
    // -> kbp*32 + q*8 + jhi*4 + jl), slot swizzle ^= d&7.
    const int vd  = t >> 3;                 // 0..63
    const int vs0 = (t & 7) * 8;            // source col (u16)
    int wv0, wv1;
    {
        const int vd7 = vd & 7;
        const int c2  = t & 7;
        const int kbp = c2 >> 2, cm = c2 & 3;
        const int qa  = (2 * cm) & 3;
        const int qb  = (2 * cm + 1) & 3;
        const int jhi = cm >> 1;
        wv0 = vd * 64 + ((kbp * 4 + qa) ^ vd7) * 8 + jhi * 4;
        wv1 = vd * 64 + ((kbp * 4 + qb) ^ vd7) * 8 + jhi * 4;
    }

    for (int part = 0; part < 2; ++part) {
        const int qt = part ? (63 - bx) : bx;
        const int q0 = qt * 64;
        const int nk = qt + 1;

        // Q fragment (B-operand: B[n=l16][k=quad*8+j]) — same for both halves
        bh8 qa0, qa1;
        {
            const u16* qrow = Qh + ((size_t)h * SEQ + q0 + wl * 16 + l16) * DK;
            qa0 = *(const bh8*)(qrow + quad * 8);
            qa1 = *(const bh8*)(qrow + 32 + quad * 8);
        }

        f4 o[4];               // O^T partial: q=l16, d=jd*16+quad*4+r
        float lsum = 0.f;
#pragma unroll
        for (int j = 0; j < 4; ++j) { f4 z = {0.f,0.f,0.f,0.f}; o[j] = z; }

        // ---- prologue: K frags tile 0 -> regs; V tile 0 -> LDS ----
        bh8 kc0 = *(const bh8*)kp[0];
        bh8 kc1 = *(const bh8*)kp[1];
        bh8 kc2 = *(const bh8*)kp[2];
        bh8 kc3 = *(const bh8*)kp[3];
        __syncthreads();       // protect Vs from previous part's readers
        {
            uint4 v0 = *(const uint4*)&Vbase[(size_t)vd * SEQ + vs0];
            uint2 c;
            c.x = v0.x; c.y = v0.y; *(uint2*)&Vs[0][wv0] = c;
            c.x = v0.z; c.y = v0.w; *(uint2*)&Vs[0][wv1] = c;
        }
        __syncthreads();       // V tile 0 resident

        int b = 0;
        for (int kt = 0; kt < nk; ++kt) {
            const bool have_next = (kt + 1 < nk);

            bh8 kn0, kn1, kn2, kn3;
            uint4 v0n;
            if (have_next) {   // prefetch next K frags + V row (regs)
                const size_t ko = (size_t)(kt + 1) * 64 * DK;
                kn0 = *(const bh8*)(kp[0] + ko);
                kn1 = *(const bh8*)(kp[1] + ko);
                kn2 = *(const bh8*)(kp[2] + ko);
                kn3 = *(const bh8*)(kp[3] + ko);
                v0n = *(const uint4*)&Vbase[(size_t)vd * SEQ + (kt + 1) * 64 + vs0];
            }

            // ---- S^T = K*Q^T (K from registers, no LDS dependency) ----
            float sv[2][4];
            __builtin_amdgcn_s_setprio(1);
            {
                f4 a = {0.f,0.f,0.f,0.f};
                a = __builtin_amdgcn_mfma_f32_16x16x32_bf16(kc0, qa0, a, 0, 0, 0);
                a = __builtin_amdgcn_mfma_f32_16x16x32_bf16(kc1, qa1, a, 0, 0, 0);
#pragma unroll
                for (int r = 0; r < 4; ++r) sv[0][r] = a[r];
                f4 c = {0.f,0.f,0.f,0.f};
                c = __builtin_amdgcn_mfma_f32_16x16x32_bf16(kc2, qa0, c, 0, 0, 0);
                c = __builtin_amdgcn_mfma_f32_16x16x32_bf16(kc3, qa1, c, 0, 0, 0);
#pragma unroll
                for (int r = 0; r < 4; ++r) sv[1][r] = c[r];
            }
            __builtin_amdgcn_s_setprio(0);
            // diagonal masking: key = (hh*2+kk)*16+quad*4+r, q-row = wl*16+l16
            if (kt == qt) {
#pragma unroll
                for (int kk = 0; kk < 2; ++kk)
#pragma unroll
                    for (int r = 0; r < 4; ++r)
                        if ((hh * 2 + kk) * 16 + quad * 4 + r > wl * 16 + l16)
                            sv[kk][r] = -1.0e30f;
            }

            // ---- p = 2^sv (Q pre-scaled) ----
            float p[2][4];
#pragma unroll
            for (int kk = 0; kk < 2; ++kk) {
                p[kk][0] = exp2f(sv[kk][0]); p[kk][1] = exp2f(sv[kk][1]);
                p[kk][2] = exp2f(sv[kk][2]); p[kk][3] = exp2f(sv[kk][3]);
                lsum += (p[kk][0] + p[kk][1]) + (p[kk][2] + p[kk][3]);
            }

            // ---- PV: 4x mfma_16x16x32 over this half's 32 keys (kbp=hh) ----
            {
                union { unsigned u[4]; bh8 v; } pc;
                pc.u[0] = pk2(p[0][0], p[0][1]);
                pc.u[1] = pk2(p[0][2], p[0][3]);
                pc.u[2] = pk2(p[1][0], p[1][1]);
                pc.u[3] = pk2(p[1][2], p[1][3]);
                const bh8 pb = pc.v;
                const int sc = hh ? sB : sA;
                __builtin_amdgcn_s_setprio(1);
#pragma unroll
                for (int jd = 0; jd < 4; ++jd) {
                    bh8 va = *(const bh8*)&Vs[b][(jd * 16 + l16) * 64 + sc];
                    o[jd] = __builtin_amdgcn_mfma_f32_16x16x32_bf16(va, pb, o[jd], 0, 0, 0);
                }
                __builtin_amdgcn_s_setprio(0);
            }

            if (have_next) {   // write next V tile, rotate K regs, flip bufs
                uint2 c;
                c.x = v0n.x; c.y = v0n.y; *(uint2*)&Vs[b ^ 1][wv0] = c;
                c.x = v0n.z; c.y = v0n.w; *(uint2*)&Vs[b ^ 1][wv1] = c;
                kc0 = kn0; kc1 = kn1; kc2 = kn2; kc3 = kn3;
                __syncthreads();   // V ds_writes drained
                b ^= 1;
            }
        }

        // ---- epilogue: quad-reduce l, merge halves via mscr, store ----
        lsum += __shfl_xor(lsum, 16);
        lsum += __shfl_xor(lsum, 32);
        // records: pair index w&3 (= wl), 64 lanes, 20 floats (16 O + 1 l);
        // stride-20 is bank-conflict-free for f4 writes (8-lane phases cover
        // all 32 banks). Writers: hh=1 waves; readers: hh=0 partner waves.
        float* scr = mscr + (((w & 3) * 64) + lane) * 20;
        if (hh) {
#pragma unroll
            for (int jd = 0; jd < 4; ++jd) *(f4*)(scr + jd * 4) = o[jd];
            scr[16] = lsum;
        }
        __syncthreads();
        if (!hh) {
#pragma unroll
            for (int jd = 0; jd < 4; ++jd) {
                f4 po = *(const f4*)(scr + jd * 4);
#pragma unroll
                for (int r = 0; r < 4; ++r) o[jd][r] += po[r];
            }
            lsum += scr[16];
            const float linv = 1.f / lsum;
            const size_t rowbase = (size_t)(q0 + wl * 16 + l16) * DMODEL + h * DK;
#pragma unroll
            for (int jd = 0; jd < 4; ++jd) {
                unsigned lo = (unsigned)f2b(o[jd][0] * linv) | ((unsigned)f2b(o[jd][1] * linv) << 16);
                unsigned hi = (unsigned)f2b(o[jd][2] * linv) | ((unsigned)f2b(o[jd][3] * linv) << 16);
                uint2 pkd; pkd.x = lo; pkd.y = hi;
                *(uint2*)&ctx[rowbase + jd * 16 + quad * 4] = pkd;   // O[row][d..d+3]
            }
        }
    }
}

// ---------------------------------------------------------------------------
extern "C" void kernel_launch(void* const* d_in, const int* in_sizes, int n_in,
                              void* d_out, int out_size, void* d_ws, size_t ws_size,
                              hipStream_t stream)
{
    const float* x  = (const float*)d_in[0];
    const float* wq = (const float*)d_in[1];
    const float* wk = (const float*)d_in[2];
    const float* wv = (const float*)d_in[3];
    const float* wo = (const float*)d_in[4];
    float* out = (float*)d_out;

    char* ws = (char*)d_ws;
    const size_t MB = 1u << 20;
    u16* xb   = (u16*)(ws);              // 8 MB  [4096][1024] bf16
    u16* wqkv = (u16*)(ws + 8  * MB);    // 6 MB  [3072][1024] bf16 (wq|wk|wv)
    u16* wob  = (u16*)(ws + 14 * MB);    // 2 MB  (contiguous after wqkv)
    u16* Qh   = (u16*)(ws + 16 * MB);    // 8 MB  [h][s][64]  (pre-scaled)
    u16* Kh   = (u16*)(ws + 24 * MB);    // 8 MB
    u16* Vtb  = (u16*)(ws + 32 * MB);    // 8 MB  [h][64][s]
    u16* ctxb = (u16*)(ws + 40 * MB);    // 8 MB  [s][1024]
    // rope table aliases ctxb (1 MB): read only by gemm<2>, which completes
    // before attn writes ctxb (stream-ordered).
    float2* rope = (float2*)(ws + 40 * MB);

    rope_build_kernel<<<(SEQ * 32) / 256, 256, 0, stream>>>(rope);

    const int NCVT = SEQ * DMODEL / 8 + 4 * (DMODEL * DMODEL / 8);   // 1048576
    cvt_all_kernel<<<NCVT / 256, 256, 0, stream>>>(x, wq, wk, wv, wo, xb, wqkv);

    dim3 gqkv(3 * DMODEL / 128, SEQ / 128);   // (24, 32) = 768 blocks
    gemm_bt<2><<<gqkv, 256, 0, stream>>>(xb, wqkv, nullptr, Qh, Kh, Vtb, rope,
                                         SEQ, 3 * DMODEL, DMODEL);

    attn_mfma_kernel<<<dim3(32, NHEADS), 512, 0, stream>>>(Qh, Kh, Vtb, ctxb);

    dim3 go(DMODEL / 64, SEQ / 128);          // (16, 32) = 512 blocks
    gemm_bt<0><<<go, 256, 0, stream>>>(ctxb, wob, out, nullptr, nullptr, nullptr,
                                       nullptr, SEQ, DMODEL, DMODEL);
}

// Round 6
// 216.710 us; speedup vs baseline: 1.3164x; 1.3164x over previous
//
#include <hip/hip_runtime.h>
#include <math.h>

#define SEQ    4096
#define DMODEL 1024
#define NHEADS 16
#define DK     64

typedef unsigned short u16;
typedef short bh8 __attribute__((ext_vector_type(8)));   // 8 x bf16 (4 VGPRs)
typedef float f4  __attribute__((ext_vector_type(4)));   // 4 x fp32
typedef float f16v __attribute__((ext_vector_type(16))); // 32x32 mfma acc

__device__ __forceinline__ u16 f2b(float f) {            // RNE
    union { float f; unsigned u; } v; v.f = f;
    unsigned u = v.u;
    return (u16)((u + 0x7FFFu + ((u >> 16) & 1u)) >> 16);
}
__device__ __forceinline__ unsigned pk2(float a, float b) {  // trunc pack 2xbf16
    union { float f; unsigned u; } ua, ub; ua.f = a; ub.f = b;
    return (ua.u >> 16) | (ub.u & 0xFFFF0000u);
}

// ---------------------------------------------------------------------------
// Merged fp32 -> bf16 convert for x and all 4 weights (one launch).
// ---------------------------------------------------------------------------
__global__ void cvt_all_kernel(const float* __restrict__ x,
                               const float* __restrict__ wq, const float* __restrict__ wk,
                               const float* __restrict__ wv, const float* __restrict__ wo,
                               u16* __restrict__ xb, u16* __restrict__ wb)
{
    const int NX = SEQ * DMODEL / 8;        // 524288 chunks of 8
    const int NW = DMODEL * DMODEL / 8;     // 131072
    int i = blockIdx.x * blockDim.x + threadIdx.x;
    if (i >= NX + 4 * NW) return;
    const float* src; u16* dst; int j;
    if (i < NX) { src = x; dst = xb; j = i; }
    else {
        int k = i - NX;
        int wsel = k >> 17;                 // NW = 2^17
        j = k & (NW - 1);
        src = (wsel == 0) ? wq : (wsel == 1) ? wk : (wsel == 2) ? wv : wo;
        dst = wb + (size_t)wsel * DMODEL * DMODEL;
    }
    const float4* p = (const float4*)src + (size_t)j * 2;
    float4 a = p[0], b = p[1];
    __align__(16) u16 r[8] = { f2b(a.x), f2b(a.y), f2b(a.z), f2b(a.w),
                               f2b(b.x), f2b(b.y), f2b(b.z), f2b(b.w) };
    *(uint4*)(dst + (size_t)j * 8) = *(const uint4*)r;
}

// ---------------------------------------------------------------------------
// bf16 MFMA GEMM (bt-form), BK=32, 4 waves.
// MODE 0: 128x64 tile, fp32 out.  MODE 2: 128x128, fused QKV epilogue
// (Q: RoPE * 0.125*log2e pre-scale -> [h][s][64]; K: RoPE -> [h][s][64];
//  V: transposed -> [h][64][s]).
// ---------------------------------------------------------------------------
template<int MODE>
__global__ __launch_bounds__(256) void gemm_bt(
    const u16* __restrict__ A, const u16* __restrict__ B,
    void* __restrict__ out, u16* __restrict__ Qh, u16* __restrict__ Kh,
    u16* __restrict__ Vt, int M, int N, int K)
{
    constexpr int BN = (MODE == 0) ? 64 : 128;
    constexpr int NJ = BN / 32;             // j-tiles per wave (2 or 4)

    __shared__ __align__(16) u16 As[128 * 32];
    __shared__ __align__(16) u16 Bs[BN * 32];

    const int t    = threadIdx.x;
    const int w    = t >> 6, lane = t & 63;
    const int quad = lane >> 4, l16 = lane & 15;
    const int wm   = w >> 1,  wn  = w & 1;
    const int m0   = blockIdx.y * 128, n0 = blockIdx.x * BN;
    const int lr   = lane >> 2;             // 0..15
    const int lc   = (lane & 3) * 8;        // 0,8,16,24

    f4 acc[4][NJ];
#pragma unroll
    for (int i = 0; i < 4; ++i)
#pragma unroll
        for (int j = 0; j < NJ; ++j) { f4 z = {0.f,0.f,0.f,0.f}; acc[i][j] = z; }

    const int c0 = 2 * w, c1 = 2 * w + 1;

    for (int k0 = 0; k0 < K; k0 += 32) {
        __builtin_amdgcn_global_load_lds(
            (const __attribute__((address_space(1))) unsigned int*)(A + (size_t)(m0 + c0*16 + lr)*K + k0 + lc),
            (__attribute__((address_space(3))) unsigned int*)(As + c0*512), 16, 0, 0);
        __builtin_amdgcn_global_load_lds(
            (const __attribute__((address_space(1))) unsigned int*)(A + (size_t)(m0 + c1*16 + lr)*K + k0 + lc),
            (__attribute__((address_space(3))) unsigned int*)(As + c1*512), 16, 0, 0);
        if (MODE == 0) {
            __builtin_amdgcn_global_load_lds(
                (const __attribute__((address_space(1))) unsigned int*)(B + (size_t)(n0 + w*16 + lr)*K + k0 + lc),
                (__attribute__((address_space(3))) unsigned int*)(Bs + w*512), 16, 0, 0);
        } else {
            __builtin_amdgcn_global_load_lds(
                (const __attribute__((address_space(1))) unsigned int*)(B + (size_t)(n0 + c0*16 + lr)*K + k0 + lc),
                (__attribute__((address_space(3))) unsigned int*)(Bs + c0*512), 16, 0, 0);
            __builtin_amdgcn_global_load_lds(
                (const __attribute__((address_space(1))) unsigned int*)(B + (size_t)(n0 + c1*16 + lr)*K + k0 + lc),
                (__attribute__((address_space(3))) unsigned int*)(Bs + c1*512), 16, 0, 0);
        }
        __syncthreads();

        bh8 af[4], bf_[NJ];
#pragma unroll
        for (int i = 0; i < 4; ++i)
            af[i] = *(const bh8*)&As[(wm*64 + i*16 + l16)*32 + quad*8];
#pragma unroll
        for (int j = 0; j < NJ; ++j)
            bf_[j] = *(const bh8*)&Bs[(wn*(BN/2) + j*16 + l16)*32 + quad*8];
#pragma unroll
        for (int i = 0; i < 4; ++i)
#pragma unroll
            for (int j = 0; j < NJ; ++j)
                acc[i][j] = __builtin_amdgcn_mfma_f32_16x16x32_bf16(af[i], bf_[j], acc[i][j], 0, 0, 0);
        __syncthreads();
    }

    if (MODE == 0) {
#pragma unroll
        for (int i = 0; i < 4; ++i) {
            const int row = m0 + wm*64 + i*16 + quad*4;
#pragma unroll
            for (int j = 0; j < NJ; ++j) {
                const int col = n0 + wn*(BN/2) + j*16 + l16;
#pragma unroll
                for (int r = 0; r < 4; ++r)
                    ((float*)out)[(size_t)(row + r) * N + col] = acc[i][j][r];
            }
        }
    } else {
        const int sect  = n0 >> 10;                   // 0=Q,1=K,2=V (block-uniform)
        const int cbase = (n0 & 1023) + wn * 64;      // 64-aligned head base
        const int hh    = cbase >> 6;                 // head (wave-uniform)
        if (sect < 2) {
            u16* dst = (sect == 0) ? Qh : Kh;
            const float qscl = (sect == 0) ? 0.18033688011112042f : 1.0f; // 0.125*log2(e)
#pragma unroll
            for (int j = 0; j < NJ; ++j) {
                const int d = j * 16 + l16;           // 0..63 within head
                const float invf2 = exp2f((float)(d & ~1) * (-13.287712379549449f / 64.0f))
                                    * 0.15915494309189535f;
#pragma unroll
                for (int i = 0; i < 4; ++i) {
                    const int srow0 = m0 + wm*64 + i*16 + quad*4;
#pragma unroll
                    for (int r = 0; r < 4; ++r) {
                        float own = acc[i][j][r];
                        float oth = __shfl_xor(own, 1);      // rope pair partner
                        float rev = (float)(srow0 + r) * invf2;
                        rev -= floorf(rev);                   // v_sin input: revolutions
                        float sn = __builtin_amdgcn_sinf(rev);
                        float cs = __builtin_amdgcn_cosf(rev);
                        float xe = (l16 & 1) ? oth : own;
                        float xo = (l16 & 1) ? own : oth;
                        float val = (l16 & 1) ? (sn * xe + cs * xo)
                                              : (cs * xe - sn * xo);
                        dst[((size_t)hh * SEQ + srow0 + r) * DK + d] = f2b(val * qscl);
                    }
                }
            }
        } else {
#pragma unroll
            for (int j = 0; j < NJ; ++j) {
                const int d = j * 16 + l16;
#pragma unroll
                for (int i = 0; i < 4; ++i) {
                    const int srow0 = m0 + wm*64 + i*16 + quad*4;
                    __align__(8) u16 pk[4];
#pragma unroll
                    for (int r = 0; r < 4; ++r) pk[r] = f2b(acc[i][j][r]);
                    *(unsigned long long*)&Vt[((size_t)hh * DK + d) * SEQ + srow0] =
                        *(const unsigned long long*)pk;
                }
            }
        }
    }
}

// ---------------------------------------------------------------------------
// MFMA flash attention, 32x32x16 restructure (R6).
// Rationale: R3 was LDS-read-throughput-bound (128 ds_read_b128/CU-step x
// ~12cyc ~= measured wall). mfma_32x32x16 doubles FLOP per fragment byte ->
// halves ds_read_b128 count per key. KV-tile = 128 keys; 8 waves =
// (kb 0..3 key-blocks) x (qb 0..1 q-blocks); per wave-step: 4 QK + 4 PV
// mfmas, 8 b128 LDS reads. K and V staged by global_load_lds (4 instrs/thd)
// with bank swizzle pre-applied to the GLOBAL source column (slot ^= row&7);
// no reg staging, no ds_writes, no per-step vmcnt(0) rotation (R5's mistake).
// P crosses the lane-half (k=lane>>5) boundary via v_permlane32_swap_b32
// pairs. Causal: exact per-sub-tile skip + element mask on diagonal tile.
// Epilogue: additive 4-way O/l merge (kb) via LDS scratch aliasing the K/V
// buffers (softmax is max-free; Q pre-scaled by 0.125*log2e, p = exp2(s)).
// Grid: flat 512, head = (id&7) + 8*((id>>3)&1) -> each XCD touches only 2
// heads (2MB K/V fits its 4MB L2; fixes the 212MB FETCH_SIZE L2-thrash).
// Block runs qt = bx then 63-bx: uniformly 33 steps of 128 keys.
// ---------------------------------------------------------------------------
__global__ __launch_bounds__(512, 4) void attn_mfma_kernel(
    const u16* __restrict__ Qh, const u16* __restrict__ Kh,
    const u16* __restrict__ Vt, u16* __restrict__ ctx)
{
    // [buf][ K: 128x64 (8192 u16) | V: 64x128 (8192 u16) ]
    __shared__ __align__(16) u16 smem[2][16384];

    const int id   = blockIdx.x;
    const int head = (id & 7) + 8 * ((id >> 3) & 1);
    const int bx   = id >> 4;                     // 0..31

    const int t    = threadIdx.x;                 // 0..511
    const int w    = t >> 6, lane = t & 63;
    const int qb   = w & 1, kb = w >> 1;          // q-subtile, key-block
    const int l31  = lane & 31, hl = lane >> 5;
    const int r7   = l31 & 7;

    const u16* Kbase = Kh + (size_t)head * SEQ * DK;
    const u16* Vbase = Vt + (size_t)head * DK * SEQ;

    // K-fragment LDS read offsets (u16): row = kb*32+l31, d-chunk c ->
    // logical 16B slot c*2+hl, physical ^= row&7 (= r7).
    int kread[4];
#pragma unroll
    for (int c = 0; c < 4; ++c)
        kread[c] = (kb * 32 + l31) * 64 + (((c * 2 + hl) ^ r7) * 8);
    // V-fragment offsets: row d = db*32+l31, slot kb*4+kc*2+hl, ^= d&7.
    int vread[2][2];
#pragma unroll
    for (int db = 0; db < 2; ++db)
#pragma unroll
        for (int kc = 0; kc < 2; ++kc)
            vread[db][kc] = (db * 32 + l31) * 128
                          + (((kb * 4 + kc * 2 + hl) ^ r7) * 8);

    // staging source offsets (thread-const; swizzle folded into source col)
    int koff[2], voff[2];
#pragma unroll
    for (int i = 0; i < 2; ++i) {
        const int krow = i * 64 + (t >> 3);       // 0..127
        koff[i] = krow * DK + (((t & 7) ^ (krow & 7)) * 8);
        const int vdr  = i * 32 + (t >> 4);       // 0..63
        voff[i] = vdr * SEQ + (((t & 15) ^ (vdr & 7)) * 8);
    }
    const int dstK = w * 512;                     // + i*4096 (u16 units)
    const int dstV = 8192 + w * 512;

#define STAGE(buf_, kbase_) do {                                               \
    _Pragma("unroll")                                                          \
    for (int i_ = 0; i_ < 2; ++i_) {                                           \
        __builtin_amdgcn_global_load_lds(                                      \
            (const __attribute__((address_space(1))) unsigned int*)            \
                (Kbase + (size_t)(kbase_) * DK + koff[i_]),                    \
            (__attribute__((address_space(3))) unsigned int*)                  \
                &smem[buf_][i_ * 4096 + dstK], 16, 0, 0);                      \
        __builtin_amdgcn_global_load_lds(                                      \
            (const __attribute__((address_space(1))) unsigned int*)            \
                (Vbase + (kbase_) + voff[i_]),                                 \
            (__attribute__((address_space(3))) unsigned int*)                  \
                &smem[buf_][i_ * 4096 + dstV], 16, 0, 0);                      \
    }                                                                          \
} while (0)

    for (int part = 0; part < 2; ++part) {
        const int qt = part ? (63 - bx) : bx;
        const int q0 = qt * 64;
        const int nt = qt / 2 + 1;
        const int qg = q0 + qb * 32 + l31;        // this lane's q row

        // Q fragments (B-operand: n=l31=q, k=hl*8+j = d within chunk)
        bh8 qa[4];
        {
            const u16* qrow = Qh + ((size_t)head * SEQ + qg) * DK;
#pragma unroll
            for (int c = 0; c < 4; ++c)
                qa[c] = *(const bh8*)(qrow + c * 16 + hl * 8);
        }

        f16v o0 = {0,0,0,0,0,0,0,0,0,0,0,0,0,0,0,0};
        f16v o1 = {0,0,0,0,0,0,0,0,0,0,0,0,0,0,0,0};
        float lsum = 0.f;

        __syncthreads();           // prev part's scratch readers done
        STAGE(0, 0);
        __syncthreads();           // tile 0 resident (vmcnt drained at barrier)

        int b = 0;
        for (int kt = 0; kt < nt; ++kt) {
            const bool have_next = (kt + 1 < nt);
            if (have_next) STAGE(b ^ 1, (kt + 1) * 128);

            const int  kbase = kt * 128;
            const bool diag  = (kt == nt - 1);
            const bool skip  = diag && (kbase + kb * 32 > q0 + qb * 32 + 31);

            if (!skip) {
                // ---- S^T = K*Q^T: one 32x32 acc, 4 d-chunks ----
                f16v s = {0,0,0,0,0,0,0,0,0,0,0,0,0,0,0,0};
                __builtin_amdgcn_s_setprio(1);
#pragma unroll
                for (int c = 0; c < 4; ++c) {
                    bh8 kf = *(const bh8*)&smem[b][kread[c]];
                    s = __builtin_amdgcn_mfma_f32_32x32x16_bf16(kf, qa[c], s, 0, 0, 0);
                }
                __builtin_amdgcn_s_setprio(0);
                if (diag) {        // key = kbase + kb*32 + (r&3)+8*(r>>2)+4*hl
#pragma unroll
                    for (int r = 0; r < 16; ++r) {
                        const int keyg = kbase + kb * 32 + (r & 3) + 8 * (r >> 2) + 4 * hl;
                        if (keyg > qg) s[r] = -1.0e30f;
                    }
                }
                // ---- p = 2^s (Q pre-scaled) ----
                float p[16];
#pragma unroll
                for (int r = 0; r < 16; ++r) { p[r] = exp2f(s[r]); lsum += p[r]; }

                // ---- per 16-key chunk: pack + permlane swap -> PV ----
#pragma unroll
                for (int kc = 0; kc < 2; ++kc) {
                    unsigned A0 = pk2(p[kc*8+0], p[kc*8+1]);  // keys kc*16+4hl+{0,1}
                    unsigned A1 = pk2(p[kc*8+2], p[kc*8+3]);  // +{2,3}
                    unsigned A2 = pk2(p[kc*8+4], p[kc*8+5]);  // kc*16+8+4hl+{0,1}
                    unsigned A3 = pk2(p[kc*8+6], p[kc*8+7]);  // +{2,3}
                    asm volatile("v_permlane32_swap_b32 %0, %1" : "+v"(A0), "+v"(A2));
                    asm volatile("v_permlane32_swap_b32 %0, %1" : "+v"(A1), "+v"(A3));
                    union { unsigned u[4]; bh8 v; } pb;
                    pb.u[0] = A0; pb.u[1] = A1; pb.u[2] = A2; pb.u[3] = A3;
                    bh8 va0 = *(const bh8*)&smem[b][8192 + vread[0][kc]];
                    bh8 va1 = *(const bh8*)&smem[b][8192 + vread[1][kc]];
                    __builtin_amdgcn_s_setprio(1);
                    o0 = __builtin_amdgcn_mfma_f32_32x32x16_bf16(va0, pb.v, o0, 0, 0, 0);
                    o1 = __builtin_amdgcn_mfma_f32_32x32x16_bf16(va1, pb.v, o1, 0, 0, 0);
                    __builtin_amdgcn_s_setprio(0);
                }
            }

            if (have_next) { __syncthreads(); b ^= 1; }
        }

        // ---- epilogue: reduce l across lane-halves; 4-way kb merge ----
        lsum += __shfl_xor(lsum, 32);
        __syncthreads();           // all smem K/V reads of this part done
        float* scr = (float*)&smem[0][0];   // 6 records x 64 lanes x 33 floats
        union { f16v v; f4 q[4]; } uo0, uo1;
        uo0.v = o0; uo1.v = o1;
        if (kb != 0) {
            float* rec = scr + (((kb - 1) * 2 + qb) * 64 + lane) * 33;
#pragma unroll
            for (int j = 0; j < 4; ++j) {
                *(f4*)(rec + j * 4)      = uo0.q[j];
                *(f4*)(rec + 16 + j * 4) = uo1.q[j];
            }
            rec[32] = lsum;
        }
        __syncthreads();
        if (kb == 0) {
#pragma unroll
            for (int jr = 0; jr < 3; ++jr) {
                const float* rec = scr + ((jr * 2 + qb) * 64 + lane) * 33;
#pragma unroll
                for (int j = 0; j < 4; ++j) {
                    f4 a = *(const f4*)(rec + j * 4);
                    f4 c = *(const f4*)(rec + 16 + j * 4);
#pragma unroll
                    for (int e = 0; e < 4; ++e) {
                        uo0.q[j][e] += a[e];
                        uo1.q[j][e] += c[e];
                    }
                }
                lsum += rec[32];
            }
            const float linv = 1.f / lsum;
            // O^T element r: d = (r&3) + 8*(r>>2) + 4*hl (+32 for o1)
            const size_t rowbase = (size_t)qg * DMODEL + head * DK;
#pragma unroll
            for (int a = 0; a < 4; ++a) {
                unsigned lo = (unsigned)f2b(uo0.q[a][0] * linv) | ((unsigned)f2b(uo0.q[a][1] * linv) << 16);
                unsigned hi = (unsigned)f2b(uo0.q[a][2] * linv) | ((unsigned)f2b(uo0.q[a][3] * linv) << 16);
                uint2 pkd; pkd.x = lo; pkd.y = hi;
                *(uint2*)&ctx[rowbase + a * 8 + 4 * hl] = pkd;
                lo = (unsigned)f2b(uo1.q[a][0] * linv) | ((unsigned)f2b(uo1.q[a][1] * linv) << 16);
                hi = (unsigned)f2b(uo1.q[a][2] * linv) | ((unsigned)f2b(uo1.q[a][3] * linv) << 16);
                pkd.x = lo; pkd.y = hi;
                *(uint2*)&ctx[rowbase + 32 + a * 8 + 4 * hl] = pkd;
            }
        }
    }
#undef STAGE
}

// ---------------------------------------------------------------------------
extern "C" void kernel_launch(void* const* d_in, const int* in_sizes, int n_in,
                              void* d_out, int out_size, void* d_ws, size_t ws_size,
                              hipStream_t stream)
{
    const float* x  = (const float*)d_in[0];
    const float* wq = (const float*)d_in[1];
    const float* wk = (const float*)d_in[2];
    const float* wv = (const float*)d_in[3];
    const float* wo = (const float*)d_in[4];
    float* out = (float*)d_out;

    char* ws = (char*)d_ws;
    const size_t MB = 1u << 20;
    u16* xb   = (u16*)(ws);              // 8 MB  [4096][1024] bf16
    u16* wqkv = (u16*)(ws + 8  * MB);    // 6 MB  [3072][1024] bf16 (wq|wk|wv)
    u16* wob  = (u16*)(ws + 14 * MB);    // 2 MB  (contiguous after wqkv)
    u16* Qh   = (u16*)(ws + 16 * MB);    // 8 MB  [h][s][64]  (pre-scaled)
    u16* Kh   = (u16*)(ws + 24 * MB);    // 8 MB
    u16* Vtb  = (u16*)(ws + 32 * MB);    // 8 MB  [h][64][s]
    u16* ctxb = (u16*)(ws + 40 * MB);    // 8 MB  [s][1024]

    const int NCVT = SEQ * DMODEL / 8 + 4 * (DMODEL * DMODEL / 8);   // 1048576
    cvt_all_kernel<<<NCVT / 256, 256, 0, stream>>>(x, wq, wk, wv, wo, xb, wqkv);

    dim3 gqkv(3 * DMODEL / 128, SEQ / 128);   // (24, 32) = 768 blocks
    gemm_bt<2><<<gqkv, 256, 0, stream>>>(xb, wqkv, nullptr, Qh, Kh, Vtb,
                                         SEQ, 3 * DMODEL, DMODEL);

    attn_mfma_kernel<<<dim3(512), 512, 0, stream>>>(Qh, Kh, Vtb, ctxb);

    dim3 go(DMODEL / 64, SEQ / 128);          // (16, 32) = 512 blocks
    gemm_bt<0><<<go, 256, 0, stream>>>(ctxb, wob, out, nullptr, nullptr, nullptr,
                                       SEQ, DMODEL, DMODEL);
}

// Round 7
// 204.057 us; speedup vs baseline: 1.3981x; 1.0620x over previous
//
#include <hip/hip_runtime.h>
#include <math.h>

#define SEQ    4096
#define DMODEL 1024
#define NHEADS 16
#define DK     64

typedef unsigned short u16;
typedef short bh8 __attribute__((ext_vector_type(8)));   // 8 x bf16 (4 VGPRs)
typedef float f4  __attribute__((ext_vector_type(4)));   // 4 x fp32
typedef float f16v __attribute__((ext_vector_type(16))); // 32x32 mfma acc

__device__ __forceinline__ u16 f2b(float f) {            // RNE
    union { float f; unsigned u; } v; v.f = f;
    unsigned u = v.u;
    return (u16)((u + 0x7FFFu + ((u >> 16) & 1u)) >> 16);
}
__device__ __forceinline__ unsigned pk2(float a, float b) {  // trunc pack 2xbf16
    union { float f; unsigned u; } ua, ub; ua.f = a; ub.f = b;
    return (ua.u >> 16) | (ub.u & 0xFFFF0000u);
}

// ---------------------------------------------------------------------------
// Merged fp32 -> bf16 convert for x and all 4 weights (one launch).
// ---------------------------------------------------------------------------
__global__ void cvt_all_kernel(const float* __restrict__ x,
                               const float* __restrict__ wq, const float* __restrict__ wk,
                               const float* __restrict__ wv, const float* __restrict__ wo,
                               u16* __restrict__ xb, u16* __restrict__ wb)
{
    const int NX = SEQ * DMODEL / 8;        // 524288 chunks of 8
    const int NW = DMODEL * DMODEL / 8;     // 131072
    int i = blockIdx.x * blockDim.x + threadIdx.x;
    if (i >= NX + 4 * NW) return;
    const float* src; u16* dst; int j;
    if (i < NX) { src = x; dst = xb; j = i; }
    else {
        int k = i - NX;
        int wsel = k >> 17;                 // NW = 2^17
        j = k & (NW - 1);
        src = (wsel == 0) ? wq : (wsel == 1) ? wk : (wsel == 2) ? wv : wo;
        dst = wb + (size_t)wsel * DMODEL * DMODEL;
    }
    const float4* p = (const float4*)src + (size_t)j * 2;
    float4 a = p[0], b = p[1];
    __align__(16) u16 r[8] = { f2b(a.x), f2b(a.y), f2b(a.z), f2b(a.w),
                               f2b(b.x), f2b(b.y), f2b(b.z), f2b(b.w) };
    *(uint4*)(dst + (size_t)j * 8) = *(const uint4*)r;
}

// ---------------------------------------------------------------------------
// bf16 MFMA GEMM (bt-form), BK=32, 4 waves, R7: prefetch-distance-1 dbuf
// (stage tile k+1 during compute of tile k; one barrier/step drains it).
// MODE 0: 128x64 tile, fp32 out.
// MODE 2: 128x128, fused QKV epilogue. B columns are staged PERMUTED within
// each 64-half (local col c holds global d = 4*l16+j for c = j*16+l16,
// i.e. staged row perm(r) = (r&64) | ((r&15)<<2) | ((r>>4)&3)), so:
//  * Q/K RoPE is intra-lane (pairs are j=0,1 / j=2,3; no shfl; one sin/cos
//    per pair), stores are coalesced 8B per (i,r)
//  * V is transposed through the (now free) 32KB staging LDS and stored as
//    16-lane x 256B contiguous runs along s.
// ---------------------------------------------------------------------------
template<int MODE>
__global__ __launch_bounds__(256) void gemm_bt(
    const u16* __restrict__ A, const u16* __restrict__ B,
    void* __restrict__ out, u16* __restrict__ Qh, u16* __restrict__ Kh,
    u16* __restrict__ Vt, int M, int N, int K)
{
    constexpr int BN  = (MODE == 0) ? 64 : 128;
    constexpr int NJ  = BN / 32;            // j-tiles per wave (2 or 4)
    constexpr int ASZ = 128 * 32;           // 4096 u16
    constexpr int BSZ = BN * 32;

    __shared__ __align__(16) u16 sh[2][ASZ + BSZ];

    const int t    = threadIdx.x;
    const int w    = t >> 6, lane = t & 63;
    const int quad = lane >> 4, l16 = lane & 15;
    const int wm   = w >> 1,  wn  = w & 1;
    const int m0   = blockIdx.y * 128, n0 = blockIdx.x * BN;
    const int lr   = lane >> 2;             // 0..15
    const int lc   = (lane & 3) * 8;        // 0,8,16,24
    const int c0   = 2 * w, c1 = 2 * w + 1;

    f4 acc[4][NJ];
#pragma unroll
    for (int i = 0; i < 4; ++i)
#pragma unroll
        for (int j = 0; j < NJ; ++j) { f4 z = {0.f,0.f,0.f,0.f}; acc[i][j] = z; }

    // per-thread staging source offsets (elements)
    const size_t aofs0 = (size_t)(m0 + c0 * 16 + lr) * K + lc;
    const size_t aofs1 = (size_t)(m0 + c1 * 16 + lr) * K + lc;
    size_t bofs0 = 0, bofs1 = 0;
    if (MODE == 0) {
        bofs0 = (size_t)(n0 + w * 16 + lr) * K + lc;
    } else {
        const int br0 = c0 * 16 + lr, br1 = c1 * 16 + lr;
        const int p0 = (br0 & 64) | ((br0 & 15) << 2) | ((br0 >> 4) & 3);
        const int p1 = (br1 & 64) | ((br1 & 15) << 2) | ((br1 >> 4) & 3);
        bofs0 = (size_t)(n0 + p0) * K + lc;
        bofs1 = (size_t)(n0 + p1) * K + lc;
    }

#define GLD(src_, dst_)                                                        \
    __builtin_amdgcn_global_load_lds(                                          \
        (const __attribute__((address_space(1))) unsigned int*)(src_),         \
        (__attribute__((address_space(3))) unsigned int*)(dst_), 16, 0, 0)

#define STAGE(buf_, k0_) do {                                                  \
    GLD(A + aofs0 + (k0_), &sh[buf_][c0 * 512]);                               \
    GLD(A + aofs1 + (k0_), &sh[buf_][c1 * 512]);                               \
    if (MODE == 0) {                                                           \
        GLD(B + bofs0 + (k0_), &sh[buf_][ASZ + w * 512]);                      \
    } else {                                                                   \
        GLD(B + bofs0 + (k0_), &sh[buf_][ASZ + c0 * 512]);                     \
        GLD(B + bofs1 + (k0_), &sh[buf_][ASZ + c1 * 512]);                     \
    }                                                                          \
} while (0)

    STAGE(0, 0);
    __syncthreads();                        // tile 0 resident

    int b = 0;
    for (int k0 = 0; k0 < K; k0 += 32) {
        if (k0 + 32 < K) STAGE(b ^ 1, k0 + 32);   // prefetch next tile

        const u16* As_ = &sh[b][0];
        const u16* Bs_ = &sh[b][ASZ];
        bh8 af[4], bf_[NJ];
#pragma unroll
        for (int i = 0; i < 4; ++i)
            af[i] = *(const bh8*)&As_[(wm * 64 + i * 16 + l16) * 32 + quad * 8];
#pragma unroll
        for (int j = 0; j < NJ; ++j)
            bf_[j] = *(const bh8*)&Bs_[(wn * (BN / 2) + j * 16 + l16) * 32 + quad * 8];
#pragma unroll
        for (int i = 0; i < 4; ++i)
#pragma unroll
            for (int j = 0; j < NJ; ++j)
                acc[i][j] = __builtin_amdgcn_mfma_f32_16x16x32_bf16(af[i], bf_[j], acc[i][j], 0, 0, 0);
        __syncthreads();                    // drains prefetch; frees buf b
        b ^= 1;
    }

    if (MODE == 0) {
#pragma unroll
        for (int i = 0; i < 4; ++i) {
            const int row = m0 + wm * 64 + i * 16 + quad * 4;
#pragma unroll
            for (int j = 0; j < NJ; ++j) {
                const int col = n0 + wn * (BN / 2) + j * 16 + l16;
#pragma unroll
                for (int r = 0; r < 4; ++r)
                    ((float*)out)[(size_t)(row + r) * N + col] = acc[i][j][r];
            }
        }
    } else {
        const int sect = n0 >> 10;                    // 0=Q,1=K,2=V
        if (sect < 2) {
            // ---- Q/K: intra-lane RoPE, coalesced 8B stores ----
            const int hh = ((n0 & 1023) + wn * 64) >> 6;
            u16* dst = (sect == 0) ? Qh : Kh;
            const float qscl = (sect == 0) ? 0.18033688011112042f : 1.0f; // 0.125*log2(e)
            const int dbase = l16 * 4;                // d = dbase + j
            const float invfA = exp2f((float)(dbase)     * (-13.287712379549449f / 64.0f))
                                * 0.15915494309189535f;
            const float invfB = exp2f((float)(dbase + 2) * (-13.287712379549449f / 64.0f))
                                * 0.15915494309189535f;
#pragma unroll
            for (int i = 0; i < 4; ++i) {
                const int srow0 = m0 + wm * 64 + i * 16 + quad * 4;
#pragma unroll
                for (int r = 0; r < 4; ++r) {
                    const int srow = srow0 + r;
                    float revA = (float)srow * invfA;  revA -= floorf(revA);
                    float revB = (float)srow * invfB;  revB -= floorf(revB);
                    const float snA = __builtin_amdgcn_sinf(revA);
                    const float csA = __builtin_amdgcn_cosf(revA);
                    const float snB = __builtin_amdgcn_sinf(revB);
                    const float csB = __builtin_amdgcn_cosf(revB);
                    const float e0 = acc[i][0][r], o0 = acc[i][1][r];
                    const float e1 = acc[i][2][r], o1 = acc[i][3][r];
                    const float v0 = (csA * e0 - snA * o0) * qscl;
                    const float v1 = (snA * e0 + csA * o0) * qscl;
                    const float v2 = (csB * e1 - snB * o1) * qscl;
                    const float v3 = (snB * e1 + csB * o1) * qscl;
                    uint2 st;
                    st.x = (unsigned)f2b(v0) | ((unsigned)f2b(v1) << 16);
                    st.y = (unsigned)f2b(v2) | ((unsigned)f2b(v3) << 16);
                    *(uint2*)&dst[((size_t)hh * SEQ + srow) * DK + dbase] = st;
                }
            }
        } else {
            // ---- V: transpose via the 32KB staging LDS, coalesced stores ----
            // scratch layout: [c_full 128][s 128] u16, 8B-slot swizzle
            // phys_s8 = s8 ^ (((c_full>>2)&7)<<2)  (bits 2-4: keeps 16B pairs
            // ordered for b128 reads; write side is 2-way/free).
            u16* scr = &sh[0][0];                     // 16384 u16 = 32KB
            const int cfb = wn * 64 + l16 * 4;        // + j
            const int xv  = (l16 & 7) << 2;           // ((cfb+j)>>2)&7 == l16&7
            __syncthreads();                          // staging reads all done
#pragma unroll
            for (int i = 0; i < 4; ++i) {
                const int s0 = wm * 64 + i * 16 + quad * 4;
                const int s8 = s0 >> 2;
#pragma unroll
                for (int j = 0; j < NJ; ++j) {
                    __align__(8) u16 pk[4];
#pragma unroll
                    for (int r = 0; r < 4; ++r) pk[r] = f2b(acc[i][j][r]);
                    *(unsigned long long*)&scr[(cfb + j) * 128 + (s8 ^ xv) * 4] =
                        *(const unsigned long long*)pk;
                }
            }
            __syncthreads();
            const int hh0 = (n0 & 1023) >> 6;
            const int sl  = t & 15;                   // s-chunk (16B each)
#pragma unroll
            for (int jj = 0; jj < 8; ++jj) {
                const int cfull = jj * 16 + (t >> 4);
                const int hd    = hh0 + (cfull >> 6);
                const int dd    = cfull & 63;
                const int rxv   = ((cfull >> 2) & 7) << 2;
                bh8 vv = *(const bh8*)&scr[cfull * 128 + ((sl * 2) ^ rxv) * 4];
                *(bh8*)&Vt[((size_t)hd * DK + dd) * SEQ + m0 + sl * 8] = vv;
            }
        }
    }
#undef STAGE
#undef GLD
}

// ---------------------------------------------------------------------------
// MFMA flash attention, 32x32x16 (unchanged from R6, which passed at 80us):
// KV-tile 128; 8 waves = (kb 0..3) x (qb 0..1); K/V staged by global_load_lds
// with source-side bank swizzle; P crosses lane-halves via permlane32_swap;
// additive 4-way O/l merge; head-per-XCD grid swizzle (FETCH 212->17MB).
// ---------------------------------------------------------------------------
__global__ __launch_bounds__(512, 4) void attn_mfma_kernel(
    const u16* __restrict__ Qh, const u16* __restrict__ Kh,
    const u16* __restrict__ Vt, u16* __restrict__ ctx)
{
    // [buf][ K: 128x64 (8192 u16) | V: 64x128 (8192 u16) ]
    __shared__ __align__(16) u16 smem[2][16384];

    const int id   = blockIdx.x;
    const int head = (id & 7) + 8 * ((id >> 3) & 1);
    const int bx   = id >> 4;                     // 0..31

    const int t    = threadIdx.x;                 // 0..511
    const int w    = t >> 6, lane = t & 63;
    const int qb   = w & 1, kb = w >> 1;          // q-subtile, key-block
    const int l31  = lane & 31, hl = lane >> 5;
    const int r7   = l31 & 7;

    const u16* Kbase = Kh + (size_t)head * SEQ * DK;
    const u16* Vbase = Vt + (size_t)head * DK * SEQ;

    int kread[4];
#pragma unroll
    for (int c = 0; c < 4; ++c)
        kread[c] = (kb * 32 + l31) * 64 + (((c * 2 + hl) ^ r7) * 8);
    int vread[2][2];
#pragma unroll
    for (int db = 0; db < 2; ++db)
#pragma unroll
        for (int kc = 0; kc < 2; ++kc)
            vread[db][kc] = (db * 32 + l31) * 128
                          + (((kb * 4 + kc * 2 + hl) ^ r7) * 8);

    int koff[2], voff[2];
#pragma unroll
    for (int i = 0; i < 2; ++i) {
        const int krow = i * 64 + (t >> 3);       // 0..127
        koff[i] = krow * DK + (((t & 7) ^ (krow & 7)) * 8);
        const int vdr  = i * 32 + (t >> 4);       // 0..63
        voff[i] = vdr * SEQ + (((t & 15) ^ (vdr & 7)) * 8);
    }
    const int dstK = w * 512;
    const int dstV = 8192 + w * 512;

#define STAGE(buf_, kbase_) do {                                               \
    _Pragma("unroll")                                                          \
    for (int i_ = 0; i_ < 2; ++i_) {                                           \
        __builtin_amdgcn_global_load_lds(                                      \
            (const __attribute__((address_space(1))) unsigned int*)            \
                (Kbase + (size_t)(kbase_) * DK + koff[i_]),                    \
            (__attribute__((address_space(3))) unsigned int*)                  \
                &smem[buf_][i_ * 4096 + dstK], 16, 0, 0);                      \
        __builtin_amdgcn_global_load_lds(                                      \
            (const __attribute__((address_space(1))) unsigned int*)            \
                (Vbase + (kbase_) + voff[i_]),                                 \
            (__attribute__((address_space(3))) unsigned int*)                  \
                &smem[buf_][i_ * 4096 + dstV], 16, 0, 0);                      \
    }                                                                          \
} while (0)

    for (int part = 0; part < 2; ++part) {
        const int qt = part ? (63 - bx) : bx;
        const int q0 = qt * 64;
        const int nt = qt / 2 + 1;
        const int qg = q0 + qb * 32 + l31;        // this lane's q row

        bh8 qa[4];
        {
            const u16* qrow = Qh + ((size_t)head * SEQ + qg) * DK;
#pragma unroll
            for (int c = 0; c < 4; ++c)
                qa[c] = *(const bh8*)(qrow + c * 16 + hl * 8);
        }

        f16v o0 = {0,0,0,0,0,0,0,0,0,0,0,0,0,0,0,0};
        f16v o1 = {0,0,0,0,0,0,0,0,0,0,0,0,0,0,0,0};
        float lsum = 0.f;

        __syncthreads();
        STAGE(0, 0);
        __syncthreads();

        int b = 0;
        for (int kt = 0; kt < nt; ++kt) {
            const bool have_next = (kt + 1 < nt);
            if (have_next) STAGE(b ^ 1, (kt + 1) * 128);

            const int  kbase = kt * 128;
            const bool diag  = (kt == nt - 1);
            const bool skip  = diag && (kbase + kb * 32 > q0 + qb * 32 + 31);

            if (!skip) {
                f16v s = {0,0,0,0,0,0,0,0,0,0,0,0,0,0,0,0};
                __builtin_amdgcn_s_setprio(1);
#pragma unroll
                for (int c = 0; c < 4; ++c) {
                    bh8 kf = *(const bh8*)&smem[b][kread[c]];
                    s = __builtin_amdgcn_mfma_f32_32x32x16_bf16(kf, qa[c], s, 0, 0, 0);
                }
                __builtin_amdgcn_s_setprio(0);
                if (diag) {
#pragma unroll
                    for (int r = 0; r < 16; ++r) {
                        const int keyg = kbase + kb * 32 + (r & 3) + 8 * (r >> 2) + 4 * hl;
                        if (keyg > qg) s[r] = -1.0e30f;
                    }
                }
                float p[16];
#pragma unroll
                for (int r = 0; r < 16; ++r) { p[r] = exp2f(s[r]); lsum += p[r]; }

#pragma unroll
                for (int kc = 0; kc < 2; ++kc) {
                    unsigned A0 = pk2(p[kc*8+0], p[kc*8+1]);
                    unsigned A1 = pk2(p[kc*8+2], p[kc*8+3]);
                    unsigned A2 = pk2(p[kc*8+4], p[kc*8+5]);
                    unsigned A3 = pk2(p[kc*8+6], p[kc*8+7]);
                    asm volatile("v_permlane32_swap_b32 %0, %1" : "+v"(A0), "+v"(A2));
                    asm volatile("v_permlane32_swap_b32 %0, %1" : "+v"(A1), "+v"(A3));
                    union { unsigned u[4]; bh8 v; } pb;
                    pb.u[0] = A0; pb.u[1] = A1; pb.u[2] = A2; pb.u[3] = A3;
                    bh8 va0 = *(const bh8*)&smem[b][8192 + vread[0][kc]];
                    bh8 va1 = *(const bh8*)&smem[b][8192 + vread[1][kc]];
                    __builtin_amdgcn_s_setprio(1);
                    o0 = __builtin_amdgcn_mfma_f32_32x32x16_bf16(va0, pb.v, o0, 0, 0, 0);
                    o1 = __builtin_amdgcn_mfma_f32_32x32x16_bf16(va1, pb.v, o1, 0, 0, 0);
                    __builtin_amdgcn_s_setprio(0);
                }
            }

            if (have_next) { __syncthreads(); b ^= 1; }
        }

        // ---- epilogue: reduce l across lane-halves; 4-way kb merge ----
        lsum += __shfl_xor(lsum, 32);
        __syncthreads();
        float* scr = (float*)&smem[0][0];
        union { f16v v; f4 q[4]; } uo0, uo1;
        uo0.v = o0; uo1.v = o1;
        if (kb != 0) {
            float* rec = scr + (((kb - 1) * 2 + qb) * 64 + lane) * 33;
#pragma unroll
            for (int j = 0; j < 4; ++j) {
                *(f4*)(rec + j * 4)      = uo0.q[j];
                *(f4*)(rec + 16 + j * 4) = uo1.q[j];
            }
            rec[32] = lsum;
        }
        __syncthreads();
        if (kb == 0) {
#pragma unroll
            for (int jr = 0; jr < 3; ++jr) {
                const float* rec = scr + ((jr * 2 + qb) * 64 + lane) * 33;
#pragma unroll
                for (int j = 0; j < 4; ++j) {
                    f4 a = *(const f4*)(rec + j * 4);
                    f4 c = *(const f4*)(rec + 16 + j * 4);
#pragma unroll
                    for (int e = 0; e < 4; ++e) {
                        uo0.q[j][e] += a[e];
                        uo1.q[j][e] += c[e];
                    }
                }
                lsum += rec[32];
            }
            const float linv = 1.f / lsum;
            const size_t rowbase = (size_t)qg * DMODEL + head * DK;
#pragma unroll
            for (int a = 0; a < 4; ++a) {
                unsigned lo = (unsigned)f2b(uo0.q[a][0] * linv) | ((unsigned)f2b(uo0.q[a][1] * linv) << 16);
                unsigned hi = (unsigned)f2b(uo0.q[a][2] * linv) | ((unsigned)f2b(uo0.q[a][3] * linv) << 16);
                uint2 pkd; pkd.x = lo; pkd.y = hi;
                *(uint2*)&ctx[rowbase + a * 8 + 4 * hl] = pkd;
                lo = (unsigned)f2b(uo1.q[a][0] * linv) | ((unsigned)f2b(uo1.q[a][1] * linv) << 16);
                hi = (unsigned)f2b(uo1.q[a][2] * linv) | ((unsigned)f2b(uo1.q[a][3] * linv) << 16);
                pkd.x = lo; pkd.y = hi;
                *(uint2*)&ctx[rowbase + 32 + a * 8 + 4 * hl] = pkd;
            }
        }
    }
#undef STAGE
}

// ---------------------------------------------------------------------------
extern "C" void kernel_launch(void* const* d_in, const int* in_sizes, int n_in,
                              void* d_out, int out_size, void* d_ws, size_t ws_size,
                              hipStream_t stream)
{
    const float* x  = (const float*)d_in[0];
    const float* wq = (const float*)d_in[1];
    const float* wk = (const float*)d_in[2];
    const float* wv = (const float*)d_in[3];
    const float* wo = (const float*)d_in[4];
    float* out = (float*)d_out;

    char* ws = (char*)d_ws;
    const size_t MB = 1u << 20;
    u16* xb   = (u16*)(ws);              // 8 MB  [4096][1024] bf16
    u16* wqkv = (u16*)(ws + 8  * MB);    // 6 MB  [3072][1024] bf16 (wq|wk|wv)
    u16* wob  = (u16*)(ws + 14 * MB);    // 2 MB  (contiguous after wqkv)
    u16* Qh   = (u16*)(ws + 16 * MB);    // 8 MB  [h][s][64]  (pre-scaled)
    u16* Kh   = (u16*)(ws + 24 * MB);    // 8 MB
    u16* Vtb  = (u16*)(ws + 32 * MB);    // 8 MB  [h][64][s]
    u16* ctxb = (u16*)(ws + 40 * MB);    // 8 MB  [s][1024]

    const int NCVT = SEQ * DMODEL / 8 + 4 * (DMODEL * DMODEL / 8);   // 1048576
    cvt_all_kernel<<<NCVT / 256, 256, 0, stream>>>(x, wq, wk, wv, wo, xb, wqkv);

    dim3 gqkv(3 * DMODEL / 128, SEQ / 128);   // (24, 32) = 768 blocks
    gemm_bt<2><<<gqkv, 256, 0, stream>>>(xb, wqkv, nullptr, Qh, Kh, Vtb,
                                         SEQ, 3 * DMODEL, DMODEL);

    attn_mfma_kernel<<<dim3(512), 512, 0, stream>>>(Qh, Kh, Vtb, ctxb);

    dim3 go(DMODEL / 64, SEQ / 128);          // (16, 32) = 512 blocks
    gemm_bt<0><<<go, 256, 0, stream>>>(ctxb, wob, out, nullptr, nullptr, nullptr,
                                       SEQ, DMODEL, DMODEL);
}

// Round 8
// 182.119 us; speedup vs baseline: 1.5665x; 1.1205x over previous
//
#include <hip/hip_runtime.h>
#include <math.h>

#define SEQ    4096
#define DMODEL 1024
#define NHEADS 16
#define DK     64

typedef unsigned short u16;
typedef short bh8 __attribute__((ext_vector_type(8)));   // 8 x bf16 (4 VGPRs)
typedef float f4  __attribute__((ext_vector_type(4)));   // 4 x fp32
typedef float f16v __attribute__((ext_vector_type(16))); // 32x32 mfma acc

__device__ __forceinline__ u16 f2b(float f) {            // RNE
    union { float f; unsigned u; } v; v.f = f;
    unsigned u = v.u;
    return (u16)((u + 0x7FFFu + ((u >> 16) & 1u)) >> 16);
}
__device__ __forceinline__ unsigned bits_of(float f) {
    union { float f; unsigned u; } v; v.f = f; return v.u;
}
// pack (a,b) -> {a.hi16, b.hi16} (trunc bf16 pair) in ONE v_perm_b32
__device__ __forceinline__ unsigned pk2(float a, float b) {
#if __has_builtin(__builtin_amdgcn_perm)
    return __builtin_amdgcn_perm(bits_of(b), bits_of(a), 0x07060302u);
#else
    return (bits_of(a) >> 16) | (bits_of(b) & 0xFFFF0000u);
#endif
}
__device__ __forceinline__ float fexp2(float x) {
#if __has_builtin(__builtin_amdgcn_exp2f)
    return __builtin_amdgcn_exp2f(x);       // raw v_exp_f32
#else
    return exp2f(x);
#endif
}
__device__ __forceinline__ float ffract(float x) {
#if __has_builtin(__builtin_amdgcn_fractf)
    return __builtin_amdgcn_fractf(x);      // raw v_fract_f32
#else
    return x - floorf(x);
#endif
}

// ---------------------------------------------------------------------------
// Merged fp32 -> bf16 convert for x and all 4 weights (one launch).
// ---------------------------------------------------------------------------
__global__ void cvt_all_kernel(const float* __restrict__ x,
                               const float* __restrict__ wq, const float* __restrict__ wk,
                               const float* __restrict__ wv, const float* __restrict__ wo,
                               u16* __restrict__ xb, u16* __restrict__ wb)
{
    const int NX = SEQ * DMODEL / 8;        // 524288 chunks of 8
    const int NW = DMODEL * DMODEL / 8;     // 131072
    int i = blockIdx.x * blockDim.x + threadIdx.x;
    if (i >= NX + 4 * NW) return;
    const float* src; u16* dst; int j;
    if (i < NX) { src = x; dst = xb; j = i; }
    else {
        int k = i - NX;
        int wsel = k >> 17;                 // NW = 2^17
        j = k & (NW - 1);
        src = (wsel == 0) ? wq : (wsel == 1) ? wk : (wsel == 2) ? wv : wo;
        dst = wb + (size_t)wsel * DMODEL * DMODEL;
    }
    const float4* p = (const float4*)src + (size_t)j * 2;
    float4 a = p[0], b = p[1];
    __align__(16) u16 r[8] = { f2b(a.x), f2b(a.y), f2b(a.z), f2b(a.w),
                               f2b(b.x), f2b(b.y), f2b(b.z), f2b(b.w) };
    *(uint4*)(dst + (size_t)j * 8) = *(const uint4*)r;
}

// ---------------------------------------------------------------------------
// bf16 MFMA GEMM (bt-form), BK=32, 4 waves, prefetch-distance-1 dbuf.
// R8: FLAT grid with XCD-affine mapping — all blocks sharing a B-tile have
// id%8 == x%8, so each XCD keeps its B panels L2-resident.
// MODE 0: 128x64 tile, fp32 out (512 blocks: x' = (g>>8)*8+(g&7), y'=(g&255)>>3).
// MODE 2: 128x128, fused QKV epilogue (768 blocks, same mapping), permuted
// B staging (intra-lane RoPE, coalesced Q/K stores), V transpose via LDS.
// ---------------------------------------------------------------------------
template<int MODE>
__global__ __launch_bounds__(256) void gemm_bt(
    const u16* __restrict__ A, const u16* __restrict__ B,
    void* __restrict__ out, u16* __restrict__ Qh, u16* __restrict__ Kh,
    u16* __restrict__ Vt, int M, int N, int K)
{
    constexpr int BN  = (MODE == 0) ? 64 : 128;
    constexpr int NJ  = BN / 32;            // j-tiles per wave (2 or 4)
    constexpr int ASZ = 128 * 32;           // 4096 u16
    constexpr int BSZ = BN * 32;

    __shared__ __align__(16) u16 sh[2][ASZ + BSZ];

    const int g    = blockIdx.x;            // flat, XCD-affine
    const int xt   = (g >> 8) * 8 + (g & 7);
    const int yt   = (g & 255) >> 3;
    const int m0   = yt * 128, n0 = xt * BN;

    const int t    = threadIdx.x;
    const int w    = t >> 6, lane = t & 63;
    const int quad = lane >> 4, l16 = lane & 15;
    const int wm   = w >> 1,  wn  = w & 1;
    const int lr   = lane >> 2;             // 0..15
    const int lc   = (lane & 3) * 8;        // 0,8,16,24
    const int c0   = 2 * w, c1 = 2 * w + 1;

    f4 acc[4][NJ];
#pragma unroll
    for (int i = 0; i < 4; ++i)
#pragma unroll
        for (int j = 0; j < NJ; ++j) { f4 z = {0.f,0.f,0.f,0.f}; acc[i][j] = z; }

    // per-thread staging source offsets (elements)
    const size_t aofs0 = (size_t)(m0 + c0 * 16 + lr) * K + lc;
    const size_t aofs1 = (size_t)(m0 + c1 * 16 + lr) * K + lc;
    size_t bofs0 = 0, bofs1 = 0;
    if (MODE == 0) {
        bofs0 = (size_t)(n0 + w * 16 + lr) * K + lc;
    } else {
        const int br0 = c0 * 16 + lr, br1 = c1 * 16 + lr;
        const int p0 = (br0 & 64) | ((br0 & 15) << 2) | ((br0 >> 4) & 3);
        const int p1 = (br1 & 64) | ((br1 & 15) << 2) | ((br1 >> 4) & 3);
        bofs0 = (size_t)(n0 + p0) * K + lc;
        bofs1 = (size_t)(n0 + p1) * K + lc;
    }

#define GLD(src_, dst_)                                                        \
    __builtin_amdgcn_global_load_lds(                                          \
        (const __attribute__((address_space(1))) unsigned int*)(src_),         \
        (__attribute__((address_space(3))) unsigned int*)(dst_), 16, 0, 0)

#define STAGE(buf_, k0_) do {                                                  \
    GLD(A + aofs0 + (k0_), &sh[buf_][c0 * 512]);                               \
    GLD(A + aofs1 + (k0_), &sh[buf_][c1 * 512]);                               \
    if (MODE == 0) {                                                           \
        GLD(B + bofs0 + (k0_), &sh[buf_][ASZ + w * 512]);                      \
    } else {                                                                   \
        GLD(B + bofs0 + (k0_), &sh[buf_][ASZ + c0 * 512]);                     \
        GLD(B + bofs1 + (k0_), &sh[buf_][ASZ + c1 * 512]);                     \
    }                                                                          \
} while (0)

    STAGE(0, 0);
    __syncthreads();                        // tile 0 resident

    int b = 0;
    for (int k0 = 0; k0 < K; k0 += 32) {
        if (k0 + 32 < K) STAGE(b ^ 1, k0 + 32);   // prefetch next tile

        const u16* As_ = &sh[b][0];
        const u16* Bs_ = &sh[b][ASZ];
        bh8 af[4], bf_[NJ];
#pragma unroll
        for (int i = 0; i < 4; ++i)
            af[i] = *(const bh8*)&As_[(wm * 64 + i * 16 + l16) * 32 + quad * 8];
#pragma unroll
        for (int j = 0; j < NJ; ++j)
            bf_[j] = *(const bh8*)&Bs_[(wn * (BN / 2) + j * 16 + l16) * 32 + quad * 8];
#pragma unroll
        for (int i = 0; i < 4; ++i)
#pragma unroll
            for (int j = 0; j < NJ; ++j)
                acc[i][j] = __builtin_amdgcn_mfma_f32_16x16x32_bf16(af[i], bf_[j], acc[i][j], 0, 0, 0);
        __syncthreads();                    // drains prefetch; frees buf b
        b ^= 1;
    }

    if (MODE == 0) {
#pragma unroll
        for (int i = 0; i < 4; ++i) {
            const int row = m0 + wm * 64 + i * 16 + quad * 4;
#pragma unroll
            for (int j = 0; j < NJ; ++j) {
                const int col = n0 + wn * (BN / 2) + j * 16 + l16;
#pragma unroll
                for (int r = 0; r < 4; ++r)
                    ((float*)out)[(size_t)(row + r) * N + col] = acc[i][j][r];
            }
        }
    } else {
        const int sect = n0 >> 10;                    // 0=Q,1=K,2=V
        if (sect < 2) {
            // ---- Q/K: intra-lane RoPE, coalesced 8B stores ----
            const int hh = ((n0 & 1023) + wn * 64) >> 6;
            u16* dst = (sect == 0) ? Qh : Kh;
            const float qscl = (sect == 0) ? 0.18033688011112042f : 1.0f; // 0.125*log2(e)
            const int dbase = l16 * 4;                // d = dbase + j
            const float invfA = exp2f((float)(dbase)     * (-13.287712379549449f / 64.0f))
                                * 0.15915494309189535f;
            const float invfB = exp2f((float)(dbase + 2) * (-13.287712379549449f / 64.0f))
                                * 0.15915494309189535f;
#pragma unroll
            for (int i = 0; i < 4; ++i) {
                const int srow0 = m0 + wm * 64 + i * 16 + quad * 4;
#pragma unroll
                for (int r = 0; r < 4; ++r) {
                    const int srow = srow0 + r;
                    const float revA = ffract((float)srow * invfA);
                    const float revB = ffract((float)srow * invfB);
                    const float snA = __builtin_amdgcn_sinf(revA);
                    const float csA = __builtin_amdgcn_cosf(revA);
                    const float snB = __builtin_amdgcn_sinf(revB);
                    const float csB = __builtin_amdgcn_cosf(revB);
                    const float e0 = acc[i][0][r], o0 = acc[i][1][r];
                    const float e1 = acc[i][2][r], o1 = acc[i][3][r];
                    const float v0 = (csA * e0 - snA * o0) * qscl;
                    const float v1 = (snA * e0 + csA * o0) * qscl;
                    const float v2 = (csB * e1 - snB * o1) * qscl;
                    const float v3 = (snB * e1 + csB * o1) * qscl;
                    uint2 st;
                    st.x = (unsigned)f2b(v0) | ((unsigned)f2b(v1) << 16);
                    st.y = (unsigned)f2b(v2) | ((unsigned)f2b(v3) << 16);
                    *(uint2*)&dst[((size_t)hh * SEQ + srow) * DK + dbase] = st;
                }
            }
        } else {
            // ---- V: transpose via the 32KB staging LDS, coalesced stores ----
            u16* scr = &sh[0][0];                     // 16384 u16 = 32KB
            const int cfb = wn * 64 + l16 * 4;        // + j
            const int xv  = (l16 & 7) << 2;           // ((cfb+j)>>2)&7 == l16&7
            __syncthreads();                          // staging reads all done
#pragma unroll
            for (int i = 0; i < 4; ++i) {
                const int s0 = wm * 64 + i * 16 + quad * 4;
                const int s8 = s0 >> 2;
#pragma unroll
                for (int j = 0; j < NJ; ++j) {
                    __align__(8) u16 pk[4];
#pragma unroll
                    for (int r = 0; r < 4; ++r) pk[r] = f2b(acc[i][j][r]);
                    *(unsigned long long*)&scr[(cfb + j) * 128 + (s8 ^ xv) * 4] =
                        *(const unsigned long long*)pk;
                }
            }
            __syncthreads();
            const int hh0 = (n0 & 1023) >> 6;
            const int sl  = t & 15;                   // s-chunk (16B each)
#pragma unroll
            for (int jj = 0; jj < 8; ++jj) {
                const int cfull = jj * 16 + (t >> 4);
                const int hd    = hh0 + (cfull >> 6);
                const int dd    = cfull & 63;
                const int rxv   = ((cfull >> 2) & 7) << 2;
                bh8 vv = *(const bh8*)&scr[cfull * 128 + ((sl * 2) ^ rxv) * 4];
                *(bh8*)&Vt[((size_t)hd * DK + dd) * SEQ + m0 + sl * 8] = vv;
            }
        }
    }
#undef STAGE
#undef GLD
}

// ---------------------------------------------------------------------------
// MFMA flash attention, 32x32x16. R8 deltas vs R7 (structure unchanged):
//  * epilogue merge scratch stride 33 -> 36 floats (bank base 4l mod 32 ->
//    conflict-free; removes the 4.2M SQ_LDS_BANK_CONFLICT cycles)
//  * QK accumulator starts from a hoisted zero vector (no 16 v_movs/step)
//  * pk2 via v_perm_b32 (1 instr), exp2 via raw v_exp_f32
// ---------------------------------------------------------------------------
__global__ __launch_bounds__(512, 4) void attn_mfma_kernel(
    const u16* __restrict__ Qh, const u16* __restrict__ Kh,
    const u16* __restrict__ Vt, u16* __restrict__ ctx)
{
    // [buf][ K: 128x64 (8192 u16) | V: 64x128 (8192 u16) ]
    __shared__ __align__(16) u16 smem[2][16384];

    const int id   = blockIdx.x;
    const int head = (id & 7) + 8 * ((id >> 3) & 1);
    const int bx   = id >> 4;                     // 0..31

    const int t    = threadIdx.x;                 // 0..511
    const int w    = t >> 6, lane = t & 63;
    const int qb   = w & 1, kb = w >> 1;          // q-subtile, key-block
    const int l31  = lane & 31, hl = lane >> 5;
    const int r7   = l31 & 7;

    const u16* Kbase = Kh + (size_t)head * SEQ * DK;
    const u16* Vbase = Vt + (size_t)head * DK * SEQ;

    int kread[4];
#pragma unroll
    for (int c = 0; c < 4; ++c)
        kread[c] = (kb * 32 + l31) * 64 + (((c * 2 + hl) ^ r7) * 8);
    int vread[2][2];
#pragma unroll
    for (int db = 0; db < 2; ++db)
#pragma unroll
        for (int kc = 0; kc < 2; ++kc)
            vread[db][kc] = (db * 32 + l31) * 128
                          + (((kb * 4 + kc * 2 + hl) ^ r7) * 8);

    int koff[2], voff[2];
#pragma unroll
    for (int i = 0; i < 2; ++i) {
        const int krow = i * 64 + (t >> 3);       // 0..127
        koff[i] = krow * DK + (((t & 7) ^ (krow & 7)) * 8);
        const int vdr  = i * 32 + (t >> 4);       // 0..63
        voff[i] = vdr * SEQ + (((t & 15) ^ (vdr & 7)) * 8);
    }
    const int dstK = w * 512;
    const int dstV = 8192 + w * 512;

    const f16v z16 = {0,0,0,0,0,0,0,0,0,0,0,0,0,0,0,0};

#define STAGE(buf_, kbase_) do {                                               \
    _Pragma("unroll")                                                          \
    for (int i_ = 0; i_ < 2; ++i_) {                                           \
        __builtin_amdgcn_global_load_lds(                                      \
            (const __attribute__((address_space(1))) unsigned int*)            \
                (Kbase + (size_t)(kbase_) * DK + koff[i_]),                    \
            (__attribute__((address_space(3))) unsigned int*)                  \
                &smem[buf_][i_ * 4096 + dstK], 16, 0, 0);                      \
        __builtin_amdgcn_global_load_lds(                                      \
            (const __attribute__((address_space(1))) unsigned int*)            \
                (Vbase + (kbase_) + voff[i_]),                                 \
            (__attribute__((address_space(3))) unsigned int*)                  \
                &smem[buf_][i_ * 4096 + dstV], 16, 0, 0);                      \
    }                                                                          \
} while (0)

    for (int part = 0; part < 2; ++part) {
        const int qt = part ? (63 - bx) : bx;
        const int q0 = qt * 64;
        const int nt = qt / 2 + 1;
        const int qg = q0 + qb * 32 + l31;        // this lane's q row

        bh8 qa[4];
        {
            const u16* qrow = Qh + ((size_t)head * SEQ + qg) * DK;
#pragma unroll
            for (int c = 0; c < 4; ++c)
                qa[c] = *(const bh8*)(qrow + c * 16 + hl * 8);
        }

        f16v o0 = z16;
        f16v o1 = z16;
        float lsum = 0.f;

        __syncthreads();
        STAGE(0, 0);
        __syncthreads();

        int b = 0;
        for (int kt = 0; kt < nt; ++kt) {
            const bool have_next = (kt + 1 < nt);
            if (have_next) STAGE(b ^ 1, (kt + 1) * 128);

            const int  kbase = kt * 128;
            const bool diag  = (kt == nt - 1);
            const bool skip  = diag && (kbase + kb * 32 > q0 + qb * 32 + 31);

            if (!skip) {
                __builtin_amdgcn_s_setprio(1);
                bh8 kf0 = *(const bh8*)&smem[b][kread[0]];
                f16v s = __builtin_amdgcn_mfma_f32_32x32x16_bf16(kf0, qa[0], z16, 0, 0, 0);
#pragma unroll
                for (int c = 1; c < 4; ++c) {
                    bh8 kf = *(const bh8*)&smem[b][kread[c]];
                    s = __builtin_amdgcn_mfma_f32_32x32x16_bf16(kf, qa[c], s, 0, 0, 0);
                }
                __builtin_amdgcn_s_setprio(0);
                if (diag) {
#pragma unroll
                    for (int r = 0; r < 16; ++r) {
                        const int keyg = kbase + kb * 32 + (r & 3) + 8 * (r >> 2) + 4 * hl;
                        if (keyg > qg) s[r] = -1.0e30f;
                    }
                }
                float p[16];
#pragma unroll
                for (int r = 0; r < 16; ++r) { p[r] = fexp2(s[r]); lsum += p[r]; }

#pragma unroll
                for (int kc = 0; kc < 2; ++kc) {
                    unsigned A0 = pk2(p[kc*8+0], p[kc*8+1]);
                    unsigned A1 = pk2(p[kc*8+2], p[kc*8+3]);
                    unsigned A2 = pk2(p[kc*8+4], p[kc*8+5]);
                    unsigned A3 = pk2(p[kc*8+6], p[kc*8+7]);
                    asm volatile("v_permlane32_swap_b32 %0, %1" : "+v"(A0), "+v"(A2));
                    asm volatile("v_permlane32_swap_b32 %0, %1" : "+v"(A1), "+v"(A3));
                    union { unsigned u[4]; bh8 v; } pb;
                    pb.u[0] = A0; pb.u[1] = A1; pb.u[2] = A2; pb.u[3] = A3;
                    bh8 va0 = *(const bh8*)&smem[b][8192 + vread[0][kc]];
                    bh8 va1 = *(const bh8*)&smem[b][8192 + vread[1][kc]];
                    __builtin_amdgcn_s_setprio(1);
                    o0 = __builtin_amdgcn_mfma_f32_32x32x16_bf16(va0, pb.v, o0, 0, 0, 0);
                    o1 = __builtin_amdgcn_mfma_f32_32x32x16_bf16(va1, pb.v, o1, 0, 0, 0);
                    __builtin_amdgcn_s_setprio(0);
                }
            }

            if (have_next) { __syncthreads(); b ^= 1; }
        }

        // ---- epilogue: reduce l across lane-halves; 4-way kb merge ----
        lsum += __shfl_xor(lsum, 32);
        __syncthreads();
        // stride 36 floats: lane bank base = 4*lane mod 32 -> f4 ops hit all
        // 32 banks exactly once per 8-lane phase (conflict-free).
        float* scr = (float*)&smem[0][0];   // 6 x 64 x 36 floats = 55296B
        union { f16v v; f4 q[4]; } uo0, uo1;
        uo0.v = o0; uo1.v = o1;
        if (kb != 0) {
            float* rec = scr + (((kb - 1) * 2 + qb) * 64 + lane) * 36;
#pragma unroll
            for (int j = 0; j < 4; ++j) {
                *(f4*)(rec + j * 4)      = uo0.q[j];
                *(f4*)(rec + 16 + j * 4) = uo1.q[j];
            }
            rec[32] = lsum;
        }
        __syncthreads();
        if (kb == 0) {
#pragma unroll
            for (int jr = 0; jr < 3; ++jr) {
                const float* rec = scr + ((jr * 2 + qb) * 64 + lane) * 36;
#pragma unroll
                for (int j = 0; j < 4; ++j) {
                    f4 a = *(const f4*)(rec + j * 4);
                    f4 c = *(const f4*)(rec + 16 + j * 4);
#pragma unroll
                    for (int e = 0; e < 4; ++e) {
                        uo0.q[j][e] += a[e];
                        uo1.q[j][e] += c[e];
                    }
                }
                lsum += rec[32];
            }
            const float linv = 1.f / lsum;
            const size_t rowbase = (size_t)qg * DMODEL + head * DK;
#pragma unroll
            for (int a = 0; a < 4; ++a) {
                unsigned lo = pk2(0.f, uo0.q[a][0] * linv) >> 16 |
                              (pk2(0.f, uo0.q[a][1] * linv) & 0xFFFF0000u);
                // use RNE f2b for output accuracy (same as before)
                lo = (unsigned)f2b(uo0.q[a][0] * linv) | ((unsigned)f2b(uo0.q[a][1] * linv) << 16);
                unsigned hi = (unsigned)f2b(uo0.q[a][2] * linv) | ((unsigned)f2b(uo0.q[a][3] * linv) << 16);
                uint2 pkd; pkd.x = lo; pkd.y = hi;
                *(uint2*)&ctx[rowbase + a * 8 + 4 * hl] = pkd;
                lo = (unsigned)f2b(uo1.q[a][0] * linv) | ((unsigned)f2b(uo1.q[a][1] * linv) << 16);
                hi = (unsigned)f2b(uo1.q[a][2] * linv) | ((unsigned)f2b(uo1.q[a][3] * linv) << 16);
                pkd.x = lo; pkd.y = hi;
                *(uint2*)&ctx[rowbase + 32 + a * 8 + 4 * hl] = pkd;
            }
        }
    }
#undef STAGE
}

// ---------------------------------------------------------------------------
extern "C" void kernel_launch(void* const* d_in, const int* in_sizes, int n_in,
                              void* d_out, int out_size, void* d_ws, size_t ws_size,
                              hipStream_t stream)
{
    const float* x  = (const float*)d_in[0];
    const float* wq = (const float*)d_in[1];
    const float* wk = (const float*)d_in[2];
    const float* wv = (const float*)d_in[3];
    const float* wo = (const float*)d_in[4];
    float* out = (float*)d_out;

    char* ws = (char*)d_ws;
    const size_t MB = 1u << 20;
    u16* xb   = (u16*)(ws);              // 8 MB  [4096][1024] bf16
    u16* wqkv = (u16*)(ws + 8  * MB);    // 6 MB  [3072][1024] bf16 (wq|wk|wv)
    u16* wob  = (u16*)(ws + 14 * MB);    // 2 MB  (contiguous after wqkv)
    u16* Qh   = (u16*)(ws + 16 * MB);    // 8 MB  [h][s][64]  (pre-scaled)
    u16* Kh   = (u16*)(ws + 24 * MB);    // 8 MB
    u16* Vtb  = (u16*)(ws + 32 * MB);    // 8 MB  [h][64][s]
    u16* ctxb = (u16*)(ws + 40 * MB);    // 8 MB  [s][1024]

    const int NCVT = SEQ * DMODEL / 8 + 4 * (DMODEL * DMODEL / 8);   // 1048576
    cvt_all_kernel<<<NCVT / 256, 256, 0, stream>>>(x, wq, wk, wv, wo, xb, wqkv);

    // flat 768 blocks, XCD-affine (x%8 == id%8): B panels L2-resident/XCD
    gemm_bt<2><<<dim3(768), 256, 0, stream>>>(xb, wqkv, nullptr, Qh, Kh, Vtb,
                                              SEQ, 3 * DMODEL, DMODEL);

    attn_mfma_kernel<<<dim3(512), 512, 0, stream>>>(Qh, Kh, Vtb, ctxb);

    // flat 512 blocks, same mapping
    gemm_bt<0><<<dim3(512), 256, 0, stream>>>(ctxb, wob, out, nullptr, nullptr, nullptr,
                                              SEQ, DMODEL, DMODEL);
}